// Round 3
// baseline (4719.060 us; speedup 1.0000x reference)
//
#include <hip/hip_runtime.h>
#include <hip/hip_bf16.h>
#include <hip/hip_fp16.h>
#include <stdint.h>
#include <type_traits>

// Problem constants
#define B_ 64
#define T_ 1024
#define I_ 256
#define H_ 512
#define G3_ 1536
#define O_ 256

typedef __attribute__((ext_vector_type(4))) float floatx4;
typedef __attribute__((ext_vector_type(8))) short short8;
typedef __attribute__((ext_vector_type(2))) _Float16 half2v;
typedef __attribute__((ext_vector_type(4))) unsigned int u32x4;

// Raw workgroup barrier: drains LDS only, NOT vmcnt. Keeps HBM/LLC ops
// (out stores, xg prefetch, packet stores) off the per-step critical path.
#define BARX() __asm__ volatile("s_waitcnt lgkmcnt(0)\n\ts_barrier" ::: "memory")

static __device__ __forceinline__ float fdot2f(uint32_t a, uint32_t b, float c) {
#if __has_builtin(__builtin_amdgcn_fdot2)
  return __builtin_amdgcn_fdot2(__builtin_bit_cast(half2v, a),
                                __builtin_bit_cast(half2v, b), c, false);
#else
  __half2 ha = __builtin_bit_cast(__half2, a);
  __half2 hb = __builtin_bit_cast(__half2, b);
  float2 fa = __half22float2(ha), fb = __half22float2(hb);
  return c + fa.x * fb.x + fa.y * fb.y;
#endif
}

static __device__ __forceinline__ float sigmoid_f(float x) {
  float e = __expf(-fabsf(x));
  float a = 1.f / (1.f + e);
  return x >= 0.f ? a : 1.f - a;
}
static __device__ __forceinline__ float tanh_f(float x) {
  float e = __expf(-2.f * fabsf(x));
  float a = (1.f - e) / (1.f + e);
  return x >= 0.f ? a : -a;
}
static __device__ __forceinline__ uint32_t pack_h2(float a, float b) {
  return (uint32_t)__half_as_ushort(__float2half(a)) |
         ((uint32_t)__half_as_ushort(__float2half(b)) << 16);
}
static __device__ __forceinline__ uint32_t pack_bf2(float a, float b) {
  return (uint32_t)__builtin_bit_cast(unsigned short, __float2bfloat16(a)) |
         ((uint32_t)__builtin_bit_cast(unsigned short, __float2bfloat16(b)) << 16);
}

// ---------------------------------------------------------------------------
// init: pack W_hh -> fp16 per-thread register blocks, combined biases, zero h.
// wpack dword index: i + 96*j + 6144*s + 49152*rc + 393216*l
//   thread (rc,s,j) owns row rc*64+j, k-slice [s*64,(s+1)*64); i = g*32+p
//   -> fp16x2 {W[g*512+rc*64+j][s*64+2p], ...[s*64+2p+1]}
// Packets need NO init: 0xAAAAAAAA poison never equals a tag (tags <= 1025).
// ---------------------------------------------------------------------------
__global__ void init_kernel(const float* __restrict__ Whh0, const float* __restrict__ Whh1,
                            const float* __restrict__ bih0, const float* __restrict__ bhh0,
                            const float* __restrict__ bih1, const float* __restrict__ bhh1,
                            uint32_t* __restrict__ wpack, float* __restrict__ biasv,
                            uint32_t* __restrict__ hstate) {
  int idx = blockIdx.x * 256 + threadIdx.x;
  if (idx < 786432) {
    int l = idx / 393216, rem = idx % 393216;
    int rc = rem / 49152;
    int rem2 = rem % 49152;
    int s = rem2 / 6144;
    int rem3 = rem2 % 6144;
    int j = rem3 / 96;
    int i = rem3 % 96;
    int g = i >> 5, pp = i & 31;
    const float* W = l ? Whh1 : Whh0;
    int row = g * 512 + rc * 64 + j;
    int k = s * 64 + pp * 2;
    uint32_t lo = __half_as_ushort(__float2half(W[(size_t)row * 512 + k]));
    uint32_t hi = __half_as_ushort(__float2half(W[(size_t)row * 512 + k + 1]));
    wpack[idx] = lo | (hi << 16);
  }
  int i2 = idx - 786432;
  if (i2 >= 0 && i2 < 3072) {
    int l = i2 / 1536, n = i2 % 1536;
    const float* bi = l ? bih1 : bih0;
    const float* bh = l ? bhh1 : bhh0;
    biasv[i2] = bi[n] + (n < 1024 ? bh[n] : 0.f);
  }
  int i3 = idx - (786432 + 3072);
  if (i3 >= 0 && i3 < 32768) hstate[i3] = 0u;
}

// ---------------------------------------------------------------------------
// GEMM: C[M,N] = A[M,K] * Bw[N,K]^T + bias, bf16 MFMA 16x16x32. (unchanged)
// ---------------------------------------------------------------------------
template <typename TA, typename TC>
__global__ __launch_bounds__(256, 2) void gemm_bt(
    const TA* __restrict__ A, const float* __restrict__ Bw,
    const float* __restrict__ bias, TC* __restrict__ C,
    int K, int lda, int ldc, int tcshift, int t0, int Ttot) {
  __shared__ unsigned short As[128 * 40];
  __shared__ unsigned short Bs[128 * 40];
  const int tid = threadIdx.x;
  const int bm = blockIdx.x, bn = blockIdx.y;
  const int r = tid >> 1, hf = tid & 1;

  const int m = bm * 128 + r;
  const long arow = (long)(m >> tcshift) * Ttot + t0 + (m & ((1 << tcshift) - 1));
  const TA* ap = A + arow * (long)lda + hf * 16;
  const int n = bn * 128 + r;
  const float* bp = Bw + (long)n * K + hf * 16;

  const int wid = tid >> 6, lane = tid & 63;
  const int wm = (wid >> 1) * 64, wn = (wid & 1) * 64;
  const int m16 = lane & 15, quad = lane >> 4;

  floatx4 acc[4][4];
#pragma unroll
  for (int i = 0; i < 4; ++i)
#pragma unroll
    for (int j = 0; j < 4; ++j) acc[i][j] = 0.f;

  for (int k0 = 0; k0 < K; k0 += 32) {
    unsigned short ta[16], tb[16];
    if constexpr (std::is_same<TA, float>::value) {
      const float4* p = (const float4*)(ap + k0);
#pragma unroll
      for (int q = 0; q < 4; ++q) {
        float4 v = p[q];
        ta[q * 4 + 0] = __builtin_bit_cast(unsigned short, __float2bfloat16(v.x));
        ta[q * 4 + 1] = __builtin_bit_cast(unsigned short, __float2bfloat16(v.y));
        ta[q * 4 + 2] = __builtin_bit_cast(unsigned short, __float2bfloat16(v.z));
        ta[q * 4 + 3] = __builtin_bit_cast(unsigned short, __float2bfloat16(v.w));
      }
    } else {
      const uint4* p = (const uint4*)(ap + k0);
      *(uint4*)&ta[0] = p[0];
      *(uint4*)&ta[8] = p[1];
    }
    {
      const float4* p = (const float4*)(bp + k0);
#pragma unroll
      for (int q = 0; q < 4; ++q) {
        float4 v = p[q];
        tb[q * 4 + 0] = __builtin_bit_cast(unsigned short, __float2bfloat16(v.x));
        tb[q * 4 + 1] = __builtin_bit_cast(unsigned short, __float2bfloat16(v.y));
        tb[q * 4 + 2] = __builtin_bit_cast(unsigned short, __float2bfloat16(v.z));
        tb[q * 4 + 3] = __builtin_bit_cast(unsigned short, __float2bfloat16(v.w));
      }
    }
    *(uint4*)&As[r * 40 + hf * 16] = *(uint4*)&ta[0];
    *(uint4*)&As[r * 40 + hf * 16 + 8] = *(uint4*)&ta[8];
    *(uint4*)&Bs[r * 40 + hf * 16] = *(uint4*)&tb[0];
    *(uint4*)&Bs[r * 40 + hf * 16 + 8] = *(uint4*)&tb[8];
    __syncthreads();
    short8 af[4], bfr[4];
#pragma unroll
    for (int mt = 0; mt < 4; ++mt)
      af[mt] = *(const short8*)&As[(wm + mt * 16 + m16) * 40 + quad * 8];
#pragma unroll
    for (int nt = 0; nt < 4; ++nt)
      bfr[nt] = *(const short8*)&Bs[(wn + nt * 16 + m16) * 40 + quad * 8];
#pragma unroll
    for (int mt = 0; mt < 4; ++mt)
#pragma unroll
      for (int nt = 0; nt < 4; ++nt)
        acc[mt][nt] = __builtin_amdgcn_mfma_f32_16x16x32_bf16(af[mt], bfr[nt],
                                                              acc[mt][nt], 0, 0, 0);
    __syncthreads();
  }
#pragma unroll
  for (int mt = 0; mt < 4; ++mt)
#pragma unroll
    for (int nt = 0; nt < 4; ++nt)
#pragma unroll
      for (int rr = 0; rr < 4; ++rr) {
        int grow = bm * 128 + wm + mt * 16 + quad * 4 + rr;
        int gcol = bn * 128 + wn + nt * 16 + m16;
        float v = acc[mt][nt][rr];
        if (bias) v += bias[gcol];
        if constexpr (std::is_same<TC, float>::value)
          C[(long)grow * ldc + gcol] = v;
        else
          C[(long)grow * ldc + gcol] = __float2half(v);
      }
}

// ---------------------------------------------------------------------------
// GRU recurrence, batch-pair WGs, REGISTER-RESIDENT weights, ONE barrier/step.
// 256 WGs: rc = blk>>5 (64-row chunk), bp = blk&31 (batches 2bp, 2bp+1).
// 512 threads: wave s = tid>>6 is k-slice [s*64,(s+1)*64); lane j = row.
// Weights: 96 dwords/thread (row j x 32 fp16-pairs x 3 gates), loaded ONCE
// via inline-asm global_load_dwordx4 ("=v" outputs are opaque SSA values the
// compiler cannot rematerialize -> guaranteed VGPRs). Round-2 evidence: plain
// C loads of read-only memory get re-issued in-loop (AMDGPU noclobber), which
// was ~100 MB/step of L2 reads — the co-bottleneck with the poll RT.
// Per step: wave s polls its own 64 packets (1/lane: b2=j>>5 batch half,
// m=j&31 pair s*32+m), drops to LDS strip (same-wave lgkm ordering), dots
// 2 batches x 3 gates x 32 pairs against register weights, writes 6 partials,
// BARX; wave0 (lane = b2*32+m: batch 2bp+b2, rows 2m,2m+1) reduces 8 slices,
// gates, publishes {h2,tag} packets, bf16 out store, xg prefetch.
// part[] parity double-buffered; publish-implies-consumed induction makes
// two-step slot reuse safe with the single barrier (identical protocol to
// the proven 4389us kernel; only the work decomposition changed).
// ---------------------------------------------------------------------------
__global__ __launch_bounds__(512, 1) void gru_rec(
    const uint32_t* __restrict__ wpack, const uint32_t* __restrict__ xgd,
    const float* __restrict__ bhh, uint32_t* __restrict__ hstate,
    uint32_t* __restrict__ outw, uint64_t* __restrict__ pkts,
    float* __restrict__ hid_out,
    int t0, int Tc, int outT, int outT0, int last) {
  const int tid = threadIdx.x;
  const int s = tid >> 6;          // wave = k-slice 0..7
  const int j = tid & 63;          // row within chunk / lane
  const int bp = blockIdx.x & 31;  // batch pair
  const int rc = blockIdx.x >> 5;  // row chunk (64 rows)
  const int b2 = j >> 5;           // batch half (gather & gates roles)
  const int m = j & 31;            // pair index within slice / row-pair
  const int bgat = 2 * bp + b2;    // batch this lane gathers/gates

  __shared__ uint32_t hb[2][8][32];       // [batch][slice][pair] fp16x2
  __shared__ float part[2][2][3][8][64];  // [parity][batch][gate][slice][row]

  // ---- weights: 96 dwords, pinned in VGPRs via opaque asm loads ----
  u32x4 W[24];
  {
    const uint32_t* wb = wpack + (((size_t)rc * 8 + s) * 64 + j) * 96;
#pragma unroll
    for (int q = 0; q < 24; ++q)
      asm volatile("global_load_dwordx4 %0, %1, off"
                   : "=v"(W[q])
                   : "v"(wb + q * 4));
    asm volatile("s_waitcnt vmcnt(0)" ::: "memory");
  }

  // ---- wave0 persistent gates state: rows 2m,2m+1 of batch bgat ----
  float hold0 = 0.f, hold1 = 0.f, bn0 = 0.f, bn1 = 0.f;
  uint32_t xrw = 0, xzw = 0, xnw = 0;
  if (s == 0) {
    uint32_t hv = hstate[bgat * 256 + rc * 32 + m];
    __half2 hh = __builtin_bit_cast(__half2, hv);
    hold0 = __half2float(hh.x);
    hold1 = __half2float(hh.y);
    bn0 = bhh[1024 + rc * 64 + 2 * m];
    bn1 = bhh[1024 + rc * 64 + 2 * m + 1];
    size_t base = ((size_t)bgat * Tc) * 768 + rc * 32 + m;
    xrw = xgd[base];
    xzw = xgd[base + 256];
    xnw = xgd[base + 512];
  }

  for (int tt = 0; tt < Tc; ++tt) {
    const int t = t0 + tt;
    // ---- acquire this wave's h strip: 1 packet per lane ----
    uint32_t hp;
    if (tt == 0) {
      hp = hstate[bgat * 256 + s * 32 + m];  // seeded by prev dispatch
    } else {
      const uint64_t* pp = &pkts[(((size_t)(t & 1)) * 64 + bgat) * 256 + s * 32 + m];
      uint64_t v;
      do {
        v = __hip_atomic_load(pp, __ATOMIC_RELAXED, __HIP_MEMORY_SCOPE_AGENT);
      } while ((uint32_t)(v >> 32) != (uint32_t)t);
      hp = (uint32_t)v;
    }
    hb[b2][s][m] = hp;  // same-wave lgkm ordering makes the reads below safe
    // ---- dots: 2 batches x 3 gates x 32 pairs, weights in registers ----
    float ar0 = 0.f, az0 = 0.f, an0 = 0.f;
    float ar1 = 0.f, az1 = 0.f, an1 = 0.f;
#pragma unroll
    for (int p4 = 0; p4 < 8; ++p4) {
      uint4 u0 = *((const uint4*)&hb[0][s][0] + p4);
      uint4 u1 = *((const uint4*)&hb[1][s][0] + p4);
      u32x4 wr = W[p4], wz = W[8 + p4], wn = W[16 + p4];
      ar0 = fdot2f(wr[0], u0.x, ar0); az0 = fdot2f(wz[0], u0.x, az0); an0 = fdot2f(wn[0], u0.x, an0);
      ar0 = fdot2f(wr[1], u0.y, ar0); az0 = fdot2f(wz[1], u0.y, az0); an0 = fdot2f(wn[1], u0.y, an0);
      ar0 = fdot2f(wr[2], u0.z, ar0); az0 = fdot2f(wz[2], u0.z, az0); an0 = fdot2f(wn[2], u0.z, an0);
      ar0 = fdot2f(wr[3], u0.w, ar0); az0 = fdot2f(wz[3], u0.w, az0); an0 = fdot2f(wn[3], u0.w, an0);
      ar1 = fdot2f(wr[0], u1.x, ar1); az1 = fdot2f(wz[0], u1.x, az1); an1 = fdot2f(wn[0], u1.x, an1);
      ar1 = fdot2f(wr[1], u1.y, ar1); az1 = fdot2f(wz[1], u1.y, az1); an1 = fdot2f(wn[1], u1.y, an1);
      ar1 = fdot2f(wr[2], u1.z, ar1); az1 = fdot2f(wz[2], u1.z, az1); an1 = fdot2f(wn[2], u1.z, an1);
      ar1 = fdot2f(wr[3], u1.w, ar1); az1 = fdot2f(wz[3], u1.w, az1); an1 = fdot2f(wn[3], u1.w, an1);
    }
    const int ps = t & 1;
    part[ps][0][0][s][j] = ar0;
    part[ps][0][1][s][j] = az0;
    part[ps][0][2][s][j] = an0;
    part[ps][1][0][s][j] = ar1;
    part[ps][1][1][s][j] = az1;
    part[ps][1][2][s][j] = an1;
    BARX();  // THE one barrier: partials slot ps complete

    if (s == 0) {
      float hr0 = 0.f, hr1 = 0.f, hz0 = 0.f, hz1 = 0.f, hn0 = 0.f, hn1 = 0.f;
#pragma unroll
      for (int ss = 0; ss < 8; ++ss) {
        float2 vr = *(const float2*)&part[ps][b2][0][ss][2 * m];
        float2 vz = *(const float2*)&part[ps][b2][1][ss][2 * m];
        float2 vn = *(const float2*)&part[ps][b2][2][ss][2 * m];
        hr0 += vr.x; hr1 += vr.y;
        hz0 += vz.x; hz1 += vz.y;
        hn0 += vn.x; hn1 += vn.y;
      }
      __half2 xr = __builtin_bit_cast(__half2, xrw);
      __half2 xz = __builtin_bit_cast(__half2, xzw);
      __half2 xn = __builtin_bit_cast(__half2, xnw);
      float r0 = sigmoid_f(__half2float(xr.x) + hr0);
      float r1 = sigmoid_f(__half2float(xr.y) + hr1);
      float z0 = sigmoid_f(__half2float(xz.x) + hz0);
      float z1 = sigmoid_f(__half2float(xz.y) + hz1);
      float n0 = tanh_f(__half2float(xn.x) + r0 * (hn0 + bn0));
      float n1 = tanh_f(__half2float(xn.y) + r1 * (hn1 + bn1));
      float h0 = (1.f - z0) * n0 + z0 * hold0;
      float h1 = (1.f - z1) * n1 + z1 * hold1;
      hold0 = h0;
      hold1 = h1;
      uint32_t hd = pack_h2(h0, h1);
      // publish: ONE 8B packet {data, tag}; no drain/fence needed
      uint64_t pk = (uint64_t)hd | ((uint64_t)(uint32_t)(t + 1) << 32);
      __hip_atomic_store(&pkts[(((size_t)((t + 1) & 1)) * 64 + bgat) * 256 + rc * 32 + m],
                         pk, __ATOMIC_RELAXED, __HIP_MEMORY_SCOPE_AGENT);
      // fire-and-forget out store (bf16 pair)
      outw[((size_t)bgat * outT + outT0 + tt) * 256 + rc * 32 + m] = pack_bf2(h0, h1);
      // prefetch next step's xg (consumed at next gates; ~full step to cover)
      if (tt + 1 < Tc) {
        size_t base = ((size_t)bgat * Tc + tt + 1) * 768 + rc * 32 + m;
        xrw = xgd[base];
        xzw = xgd[base + 256];
        xnw = xgd[base + 512];
      }
    }
  }

  if (s == 0) {
    hstate[bgat * 256 + rc * 32 + m] = pack_h2(hold0, hold1);
    if (last) {
      float2 hv = make_float2(hold0, hold1);
      *(float2*)&hid_out[bgat * 512 + (rc * 32 + m) * 2] = hv;
    }
  }
}

// ---------------------------------------------------------------------------
extern "C" void kernel_launch(void* const* d_in, const int* in_sizes, int n_in,
                              void* d_out, int out_size, void* d_ws, size_t ws_size,
                              hipStream_t stream) {
  const float* x = (const float*)d_in[0];
  const float* W_ih0 = (const float*)d_in[1];
  const float* W_hh0 = (const float*)d_in[2];
  const float* b_ih0 = (const float*)d_in[3];
  const float* b_hh0 = (const float*)d_in[4];
  const float* W_ih1 = (const float*)d_in[5];
  const float* W_hh1 = (const float*)d_in[6];
  const float* b_ih1 = (const float*)d_in[7];
  const float* b_hh1 = (const float*)d_in[8];
  const float* fc_w = (const float*)d_in[9];
  const float* fc_b = (const float*)d_in[10];
  float* out = (float*)d_out;

  char* p = (char*)d_ws;
  size_t off = 0;
  auto alloc = [&](size_t bytes) -> void* {
    void* r = p + off;
    off = (off + bytes + 255) & ~(size_t)255;
    return r;
  };
  uint32_t* wpack = (uint32_t*)alloc((size_t)786432 * 4);
  float* biasv = (float*)alloc((size_t)3072 * 4);
  uint32_t* hstate = (uint32_t*)alloc((size_t)32768 * 4);
  // packets: 2 layers x 2 slots x 64 batch x 256 pairs x u64
  uint64_t* pkts = (uint64_t*)alloc((size_t)2 * 2 * 64 * 256 * 8);
  __hip_bfloat16* out1 = (__hip_bfloat16*)alloc((size_t)B_ * T_ * H_ * 2);

  int Tc = 1024;
  while (Tc > 64) {
    size_t need = (size_t)B_ * Tc * H_ * 2 + (size_t)B_ * Tc * G3_ * 2 + 1024;
    if (off + need <= ws_size) break;
    Tc >>= 1;
  }
  __hip_bfloat16* out0c = (__hip_bfloat16*)alloc((size_t)B_ * Tc * H_ * 2);
  __half* xg = (__half*)alloc((size_t)B_ * Tc * G3_ * 2);
  int tcs = __builtin_ctz(Tc);

  init_kernel<<<3212, 256, 0, stream>>>(W_hh0, W_hh1, b_ih0, b_hh0, b_ih1, b_hh1,
                                        wpack, biasv, hstate);

  for (int t0 = 0; t0 < 1024; t0 += Tc) {
    const int M = B_ * Tc;
    const int last = (t0 + Tc) == 1024;
    // ---- layer 0 ----
    {
      dim3 gg(M / 128, G3_ / 128);
      gemm_bt<float, __half><<<gg, 256, 0, stream>>>(x, W_ih0, biasv, xg, I_, I_,
                                                     G3_, tcs, t0, 1024);
      gru_rec<<<256, 512, 0, stream>>>(wpack, (const uint32_t*)xg, b_hh0, hstate,
                                       (uint32_t*)out0c, pkts,
                                       out + 16777216, t0, Tc, Tc, 0, last);
    }
    // ---- layer 1 ----
    {
      dim3 gg(M / 128, G3_ / 128);
      gemm_bt<__hip_bfloat16, __half><<<gg, 256, 0, stream>>>(
          out0c, W_ih1, biasv + 1536, xg, H_, H_, G3_, tcs, 0, Tc);
      gru_rec<<<256, 512, 0, stream>>>(wpack + 393216, (const uint32_t*)xg, b_hh1,
                                       hstate + 16384, (uint32_t*)out1,
                                       pkts + 32768,
                                       out + 16777216 + 32768, t0, Tc, 1024, t0, last);
    }
  }
  // FC: [65536,512] x fc_w[256,512]^T + fc_b -> d_out fp32
  dim3 gf(65536 / 128, O_ / 128);
  gemm_bt<__hip_bfloat16, float><<<gf, 256, 0, stream>>>(out1, fc_w, fc_b, out,
                                                         H_, H_, O_, 10, 0, 1024);
}